// Round 1
// 475.962 us; speedup vs baseline: 1.0681x; 1.0681x over previous
//
#include <hip/hip_runtime.h>

#define NE 8          // routed experts
#define HD 1024       // hidden
#define MD 2048       // intermediate
#define NT 2048       // tokens (2*1024)
#define NSH 4096      // shared-expert row base (= NT * topk)

typedef __attribute__((ext_vector_type(8))) short s16x8;
typedef __attribute__((ext_vector_type(4))) float f32x4;
typedef __attribute__((ext_vector_type(8))) unsigned short u16x8;
typedef __attribute__((ext_vector_type(4))) unsigned short u16x4;

__device__ __forceinline__ unsigned short f2bf(float f) {
    union { float f; unsigned int i; } v; v.f = f;
    unsigned int u = v.i;
    return (unsigned short)((u + 0x7FFFu + ((u >> 16) & 1u)) >> 16);
}
__device__ __forceinline__ float bf2f(unsigned short u) {
    union { unsigned int i; float f; } v; v.i = ((unsigned int)u) << 16; return v.f;
}

// async 16B global -> LDS (HW adds lane*16 to wave-uniform LDS base)
__device__ __forceinline__ void gld16(const unsigned short* g, short* l) {
    __builtin_amdgcn_global_load_lds(
        (const __attribute__((address_space(1))) unsigned int*)g,
        (__attribute__((address_space(3))) unsigned int*)l,
        16, 0, 0);
}

// ---------------- K0a: fp32 -> bf16 bulk convert (x only) ----------------
__global__ __launch_bounds__(256) void k_cvt(
    const float* __restrict__ s, unsigned short* __restrict__ d, int n)
{
    int i = (blockIdx.x * 256 + threadIdx.x) * 4;
    int stride = gridDim.x * 256 * 4;
    for (; i < n; i += stride) {
        float4 v = *(const float4*)(s + i);
        u16x4 o;
        o[0] = f2bf(v.x); o[1] = f2bf(v.y); o[2] = f2bf(v.z); o[3] = f2bf(v.w);
        *(u16x4*)(d + i) = o;
    }
}

// ---------------- K0b: fp32 [e][K][N] -> bf16 [e][N*rstride][K] transpose-convert
// rstride/roff let gate and up interleave into one B^T buffer:
//   dst row for weight-col n = n*rstride + roff
__global__ __launch_bounds__(256) void k_cvt_t(
    const float* __restrict__ wr, const float* __restrict__ wsd,
    unsigned short* __restrict__ o, int K, int N, int rstride, int roff)
{
    int e = blockIdx.z;
    const float* src = (e < NE) ? wr + (size_t)e * K * N : wsd;
    unsigned short* dst = o + (size_t)e * N * K * rstride;
    int k0 = blockIdx.x * 32, n0 = blockIdx.y * 128;
    __shared__ float T[32 * 132];   // stride 132: write-phase k-stride hits 2-way max
    int tid = threadIdx.x;
    #pragma unroll
    for (int p = 0; p < 4; p++) {
        int k = (tid >> 5) + p * 8;
        int n4 = (tid & 31) * 4;
        float4 v = *(const float4*)(src + (size_t)(k0 + k) * N + n0 + n4);
        *(float4*)(&T[k * 132 + n4]) = v;
    }
    __syncthreads();
    #pragma unroll
    for (int p = 0; p < 2; p++) {
        int idx = tid + p * 256;
        int n = idx >> 2;
        int kq = (idx & 3) * 8;
        u16x8 r;
        #pragma unroll
        for (int j = 0; j < 8; j++) r[j] = f2bf(T[(kq + j) * 132 + n]);
        *(u16x8*)(dst + ((size_t)(n0 + n) * rstride + roff) * K + k0 + kq) = r;
    }
}

// ---------------- K1: routing (one wave per token, fp32) ----------------
__global__ __launch_bounds__(256) void k_route(
    const float* __restrict__ x, const float* __restrict__ gw,
    const float* __restrict__ beta,
    int* __restrict__ cnt, int* __restrict__ list, int* __restrict__ slot,
    float* __restrict__ rprob)
{
    int wave = threadIdx.x >> 6, lane = threadIdx.x & 63;
    int t = blockIdx.x * 4 + wave;
    const float4* xp = (const float4*)(x + (size_t)t * HD) + lane * 4;
    float4 xv[4];
    #pragma unroll
    for (int j = 0; j < 4; j++) xv[j] = xp[j];

    float logit[NE];
    #pragma unroll
    for (int e = 0; e < NE; e++) {
        const float4* gp = (const float4*)(gw + e * HD) + lane * 4;
        float s = 0.f;
        #pragma unroll
        for (int j = 0; j < 4; j++) {
            float4 g = gp[j];
            s += xv[j].x * g.x + xv[j].y * g.y + xv[j].z * g.z + xv[j].w * g.w;
        }
        for (int off = 32; off > 0; off >>= 1) s += __shfl_xor(s, off);
        logit[e] = s;
    }
    if (lane == 0) {
        float v[NE];
        #pragma unroll
        for (int e = 0; e < NE; e++) v[e] = logit[e] + beta[e];
        int i1 = 0; float m1 = v[0];
        #pragma unroll
        for (int e = 1; e < NE; e++) if (v[e] > m1) { m1 = v[e]; i1 = e; }
        int i2 = -1; float m2 = -3.4e38f;
        #pragma unroll
        for (int e = 0; e < NE; e++) if (e != i1 && v[e] > m2) { m2 = v[e]; i2 = e; }
        if (i2 < 0) i2 = (i1 + 1) & 7;
        float p1 = 1.f / (1.f + __expf(-logit[i1]));
        float p2 = 1.f / (1.f + __expf(-logit[i2]));
        int pos1 = atomicAdd(cnt + i1, 1);
        list[i1 * NT + pos1] = t; slot[t * 2 + 0] = (i1 << 16) | pos1; rprob[t * 2 + 0] = p1;
        int pos2 = atomicAdd(cnt + i2, 1);
        list[i2 * NT + pos2] = t; slot[t * 2 + 1] = (i2 << 16) | pos2; rprob[t * 2 + 1] = p2;
    }
}

// ---------------- K2: tiny scan for row bases ----------------
__global__ void k_scan(const int* __restrict__ cnt, int* __restrict__ base) {
    if (threadIdx.x == 0) {
        int run = 0;
        for (int e = 0; e < NE; e++) { base[e] = run; run += cnt[e]; }
        base[NE] = run;
    }
}

// ---------------- K3: gathered gate+up GEMM over interleaved B (N = 2*MD) ---
// Single B staging matrix; col parity = gate/up. LDS 33.3KB -> 4 blocks/CU.
// Chunk-XOR swizzle (source-side for global_load_lds, same XOR on ds_read).
__global__ __launch_bounds__(256, 4) void k_gateup(
    const unsigned short* __restrict__ x,
    const unsigned short* __restrict__ wgu,
    const int* __restrict__ cnt, const int* __restrict__ base, const int* __restrict__ list,
    unsigned short* __restrict__ h)
{
    int e = blockIdx.z;
    int i0 = blockIdx.y * 128;
    int n0 = blockIdx.x * 128;              // interleaved col space [0, 2*MD)
    int cnte = (e < NE) ? cnt[e] : NT;
    if (i0 >= cnte) return;
    int rbase = (e < NE) ? base[e] : NSH;
    const unsigned short* wb = wgu + (size_t)e * (2 * MD) * HD;

    __shared__ short As[2][128 * 32];
    __shared__ short Bs[2][128 * 32];
    __shared__ int tok[128];

    int tid = threadIdx.x;
    int lane = tid & 63, wave = tid >> 6;
    if (tid < 128) {
        int gi = i0 + tid;
        tok[tid] = (e < NE) ? ((gi < cnte) ? list[e * NT + gi] : list[e * NT]) : gi;
    }
    __syncthreads();

    int rr = wave * 32 + (lane >> 2);
    // source-side chunk swizzle: row bits 1-2 ((lane>>3)&3) XOR'd into chunk slot
    int kc = ((lane & 3) ^ ((lane >> 3) & 3)) * 8;
    size_t gaA0 = (size_t)tok[rr] * HD + kc;
    size_t gaA1 = (size_t)tok[rr + 16] * HD + kc;
    size_t gaB0 = (size_t)(n0 + rr) * HD + kc;
    size_t gaB1 = (size_t)(n0 + rr + 16) * HD + kc;
    int lo0 = (wave * 32) * 32, lo1 = (wave * 32 + 16) * 32;

    int wr = (wave >> 1) * 64, wc = (wave & 1) * 64;
    int m = lane & 15, q = lane >> 4;
    int sa = (m >> 1) & 3;                  // read-side swizzle (row bits 1-2)

    f32x4 acc[4][4];
    #pragma unroll
    for (int a = 0; a < 4; a++)
        #pragma unroll
        for (int b = 0; b < 4; b++) acc[a][b] = (f32x4)0.f;

    // prologue: prefetch k0=0 into buffer 0
    gld16(x + gaA0, &As[0][lo0]);
    gld16(x + gaA1, &As[0][lo1]);
    gld16(wb + gaB0, &Bs[0][lo0]);
    gld16(wb + gaB1, &Bs[0][lo1]);

    int it = 0;
    for (int k0 = 0; k0 < HD; k0 += 32, it ^= 1) {
        __syncthreads();   // drains this buf's prefetch (issued one iter ago)
        int nk = k0 + 32;
        if (nk < HD) {     // prefetch next tile into the idle buffer
            int nb = it ^ 1;
            gld16(x + gaA0 + nk, &As[nb][lo0]);
            gld16(x + gaA1 + nk, &As[nb][lo1]);
            gld16(wb + gaB0 + nk, &Bs[nb][lo0]);
            gld16(wb + gaB1 + nk, &Bs[nb][lo1]);
        }
        s16x8 af[4];
        #pragma unroll
        for (int ti = 0; ti < 4; ti++)
            af[ti] = *(const s16x8*)(&As[it][(wr + ti * 16 + m) * 32 + (q ^ sa) * 8]);
        #pragma unroll
        for (int tj = 0; tj < 4; tj++) {
            int nn = wc + tj * 16 + m;
            s16x8 bf = *(const s16x8*)(&Bs[it][nn * 32 + (q ^ sa) * 8]);
            #pragma unroll
            for (int ti = 0; ti < 4; ti++)
                acc[ti][tj] = __builtin_amdgcn_mfma_f32_16x16x32_bf16(af[ti], bf, acc[ti][tj], 0, 0, 0);
        }
    }
    // epilogue: pair gate/up across adjacent lanes (col parity == lane parity),
    // even lanes write silu(g)*u. D layout: row = q*4+r, col = m.
    #pragma unroll
    for (int ti = 0; ti < 4; ti++)
        #pragma unroll
        for (int tj = 0; tj < 4; tj++)
            #pragma unroll
            for (int r = 0; r < 4; r++) {
                float v = acc[ti][tj][r];
                float uo = __shfl_xor(v, 1);    // all lanes: keep shfl uniform
                int gi = i0 + wr + ti * 16 + q * 4 + r;
                if (!(m & 1) && gi < cnte) {
                    float g = v;
                    float hv = (g / (1.f + __expf(-g))) * uo;
                    int colI = n0 + wc + tj * 16 + m;
                    h[(size_t)(rbase + gi) * MD + (colI >> 1)] = f2bf(hv);
                }
            }
}

// ---------------- K4: down projection, double-buffered async staging ------
__global__ __launch_bounds__(256, 4) void k_down(
    const unsigned short* __restrict__ wd_all,
    const int* __restrict__ cnt, const int* __restrict__ base,
    const unsigned short* __restrict__ h, unsigned short* __restrict__ eo)
{
    int e = blockIdx.z;
    int i0 = blockIdx.y * 128;
    int n0 = blockIdx.x * 128;
    int cnte = (e < NE) ? cnt[e] : NT;
    if (i0 >= cnte) return;
    int rbase = (e < NE) ? base[e] : NSH;
    const unsigned short* wd = wd_all + (size_t)e * MD * HD;

    __shared__ short As[2][128 * 32];
    __shared__ short Bd[2][128 * 32];

    int tid = threadIdx.x;
    int lane = tid & 63, wave = tid >> 6;
    int rr = wave * 32 + (lane >> 2);
    int kc = ((lane & 3) ^ ((lane >> 3) & 3)) * 8;   // source-side chunk swizzle
    size_t gaA0 = (size_t)(rbase + i0 + rr) * MD + kc;
    size_t gaA1 = (size_t)(rbase + i0 + rr + 16) * MD + kc;
    size_t gaB0 = (size_t)(n0 + rr) * MD + kc;
    size_t gaB1 = (size_t)(n0 + rr + 16) * MD + kc;
    int lo0 = (wave * 32) * 32, lo1 = (wave * 32 + 16) * 32;

    int wr = (wave >> 1) * 64, wc = (wave & 1) * 64;
    int m = lane & 15, q = lane >> 4;
    int sa = (m >> 1) & 3;

    f32x4 acc[4][4];
    #pragma unroll
    for (int a = 0; a < 4; a++)
        #pragma unroll
        for (int b = 0; b < 4; b++) acc[a][b] = (f32x4)0.f;

    gld16(h + gaA0, &As[0][lo0]);
    gld16(h + gaA1, &As[0][lo1]);
    gld16(wd + gaB0, &Bd[0][lo0]);
    gld16(wd + gaB1, &Bd[0][lo1]);

    int it = 0;
    for (int k0 = 0; k0 < MD; k0 += 32, it ^= 1) {
        __syncthreads();
        int nk = k0 + 32;
        if (nk < MD) {
            int nb = it ^ 1;
            gld16(h + gaA0 + nk, &As[nb][lo0]);
            gld16(h + gaA1 + nk, &As[nb][lo1]);
            gld16(wd + gaB0 + nk, &Bd[nb][lo0]);
            gld16(wd + gaB1 + nk, &Bd[nb][lo1]);
        }
        s16x8 af[4];
        #pragma unroll
        for (int ti = 0; ti < 4; ti++)
            af[ti] = *(const s16x8*)(&As[it][(wr + ti * 16 + m) * 32 + (q ^ sa) * 8]);
        #pragma unroll
        for (int tj = 0; tj < 4; tj++) {
            int nn = wc + tj * 16 + m;
            s16x8 bd = *(const s16x8*)(&Bd[it][nn * 32 + (q ^ sa) * 8]);
            #pragma unroll
            for (int ti = 0; ti < 4; ti++)
                acc[ti][tj] = __builtin_amdgcn_mfma_f32_16x16x32_bf16(af[ti], bd, acc[ti][tj], 0, 0, 0);
        }
    }
    #pragma unroll
    for (int ti = 0; ti < 4; ti++)
        #pragma unroll
        for (int tj = 0; tj < 4; tj++)
            #pragma unroll
            for (int r = 0; r < 4; r++) {
                int gi = i0 + wr + ti * 16 + q * 4 + r;
                if (gi < cnte) {
                    int col = n0 + wc + tj * 16 + m;
                    eo[(size_t)(rbase + gi) * HD + col] = f2bf(acc[ti][tj][r]);
                }
            }
}

// ---------------- K5: weighted combine -> fp32 out ----------------
__global__ __launch_bounds__(256) void k_combine(
    const unsigned short* __restrict__ eo, const int* __restrict__ slot,
    const float* __restrict__ rprob, const int* __restrict__ base,
    float* __restrict__ out)
{
    int t = blockIdx.x;
    int s0 = slot[t * 2], s1 = slot[t * 2 + 1];
    float p0 = rprob[t * 2], p1 = rprob[t * 2 + 1];
    int r0 = base[s0 >> 16] + (s0 & 0xFFFF);
    int r1 = base[s1 >> 16] + (s1 & 0xFFFF);
    int rs = NSH + t;
    int c = threadIdx.x * 4;
    u16x4 a = *(const u16x4*)(eo + (size_t)r0 * HD + c);
    u16x4 b = *(const u16x4*)(eo + (size_t)r1 * HD + c);
    u16x4 s = *(const u16x4*)(eo + (size_t)rs * HD + c);
    float4 res;
    res.x = p0 * bf2f(a[0]) + p1 * bf2f(b[0]) + bf2f(s[0]);
    res.y = p0 * bf2f(a[1]) + p1 * bf2f(b[1]) + bf2f(s[1]);
    res.z = p0 * bf2f(a[2]) + p1 * bf2f(b[2]) + bf2f(s[2]);
    res.w = p0 * bf2f(a[3]) + p1 * bf2f(b[3]) + bf2f(s[3]);
    *(float4*)(out + (size_t)t * HD + c) = res;
}

extern "C" void kernel_launch(void* const* d_in, const int* in_sizes, int n_in,
                              void* d_out, int out_size, void* d_ws, size_t ws_size,
                              hipStream_t stream)
{
    const float* x    = (const float*)d_in[0];
    const float* gw   = (const float*)d_in[1];
    const float* beta = (const float*)d_in[2];
    const float* wg   = (const float*)d_in[3];
    const float* wu   = (const float*)d_in[4];
    const float* wd   = (const float*)d_in[5];
    const float* swg  = (const float*)d_in[6];
    const float* swu  = (const float*)d_in[7];
    const float* swd  = (const float*)d_in[8];
    float* out = (float*)d_out;

    char* ws = (char*)d_ws;
    const size_t MB = (size_t)1 << 20;
    int*   cnt   = (int*)(ws + 0);
    int*   basep = (int*)(ws + 64);
    int*   list  = (int*)(ws + 1024);
    int*   slot  = (int*)(ws + 1024 + 65536);
    float* rprob = (float*)(ws + 1024 + 65536 + 16384);
    unsigned short* xb   = (unsigned short*)(ws + 1 * MB);
    unsigned short* wgut = (unsigned short*)(ws + 8 * MB);   // [9][4096][1024] interleaved gate/up
    unsigned short* wdt  = (unsigned short*)(ws + 84 * MB);  // [9][1024][2048]
    unsigned short* h    = (unsigned short*)(ws + 122 * MB); // [6144][2048]
    unsigned short* eo   = (unsigned short*)(ws + 146 * MB); // [6144][1024]

    hipMemsetAsync(ws, 0, 128, stream);

    const int NX = NT * HD;
    k_cvt<<<512, 256, 0, stream>>>(x, xb, NX);

    dim3 tgu(HD / 32, MD / 128, NE + 1);  // K=1024,N=2048
    k_cvt_t<<<tgu, 256, 0, stream>>>(wg, swg, wgut, HD, MD, 2, 0);  // gate -> even rows
    k_cvt_t<<<tgu, 256, 0, stream>>>(wu, swu, wgut, HD, MD, 2, 1);  // up   -> odd rows
    dim3 td(MD / 32, HD / 128, NE + 1);   // K=2048,N=1024
    k_cvt_t<<<td, 256, 0, stream>>>(wd, swd, wdt, MD, HD, 1, 0);

    k_route<<<NT / 4, 256, 0, stream>>>(x, gw, beta, cnt, list, slot, rprob);
    k_scan<<<1, 64, 0, stream>>>(cnt, basep);

    dim3 g3(2 * MD / 128, NT / 128, NE + 1);   // 32 x 16 x 9, interleaved N=4096
    k_gateup<<<g3, 256, 0, stream>>>(xb, wgut, cnt, basep, list, h);

    dim3 g4(HD / 128, NT / 128, NE + 1);
    k_down<<<g4, 256, 0, stream>>>(wdt, cnt, basep, h, eo);

    k_combine<<<NT, 256, 0, stream>>>(eo, slot, rprob, basep, out);
}

// Round 2
// 450.928 us; speedup vs baseline: 1.1274x; 1.0555x over previous
//
#include <hip/hip_runtime.h>

#define NE 8          // routed experts
#define HD 1024       // hidden
#define MD 2048       // intermediate
#define NT 2048       // tokens (2*1024)
#define NSH 4224      // shared-expert row base (>= padded routed rows, %16==0)

typedef __attribute__((ext_vector_type(8))) short s16x8;
typedef __attribute__((ext_vector_type(4))) float f32x4;
typedef __attribute__((ext_vector_type(8))) unsigned short u16x8;
typedef __attribute__((ext_vector_type(4))) unsigned short u16x4;

__device__ __forceinline__ unsigned short f2bf(float f) {
    union { float f; unsigned int i; } v; v.f = f;
    unsigned int u = v.i;
    return (unsigned short)((u + 0x7FFFu + ((u >> 16) & 1u)) >> 16);
}
__device__ __forceinline__ float bf2f(unsigned short u) {
    union { unsigned int i; float f; } v; v.i = ((unsigned int)u) << 16; return v.f;
}

// async 16B global -> LDS (HW adds lane*16 to wave-uniform LDS base)
__device__ __forceinline__ void gld16(const unsigned short* g, short* l) {
    __builtin_amdgcn_global_load_lds(
        (const __attribute__((address_space(1))) unsigned int*)g,
        (__attribute__((address_space(3))) unsigned int*)l,
        16, 0, 0);
}

// Blocked bf16 layout for B-operands and h:
//   elem(r, k) at ((r>>4)*(K>>3) + (k>>3))*128 + (r&15)*8 + (k&7)
// A 16-row x 32-k slab is 1KB contiguous = one wave's global_load_lds.

// ---------------- K0a: fp32 -> bf16 bulk convert (x only) ----------------
__global__ __launch_bounds__(256) void k_cvt(
    const float* __restrict__ s, unsigned short* __restrict__ d, int n)
{
    int i = (blockIdx.x * 256 + threadIdx.x) * 4;
    int stride = gridDim.x * 256 * 4;
    for (; i < n; i += stride) {
        float4 v = *(const float4*)(s + i);
        u16x4 o;
        o[0] = f2bf(v.x); o[1] = f2bf(v.y); o[2] = f2bf(v.z); o[3] = f2bf(v.w);
        *(u16x4*)(d + i) = o;
    }
}

// ---------------- K0b: gate+up fp32 [e][K][M] -> interleaved blocked bf16 --
// n_i = 2*n + mat (gate even, up odd); tile 64k x 32n_src (covers 64 n_i).
// Writes: 1KB contiguous runs per wave. Reads: 128B runs.
__global__ __launch_bounds__(256) void k_cvt_gu(
    const float* __restrict__ wg, const float* __restrict__ wu,
    const float* __restrict__ swg, const float* __restrict__ swu,
    unsigned short* __restrict__ o)
{
    int e = blockIdx.z;
    const float* sg = (e < NE) ? wg + (size_t)e * HD * MD : swg;
    const float* su = (e < NE) ? wu + (size_t)e * HD * MD : swu;
    unsigned short* dst = o + (size_t)e * (2 * MD) * HD;
    int k0 = blockIdx.x * 64, n0s = blockIdx.y * 32;
    __shared__ float T[64 * 67];   // cols 0..31 gate, 32..63 up; pad 67
    int tid = threadIdx.x;
    #pragma unroll
    for (int p = 0; p < 4; p++) {
        int idx = p * 256 + tid;
        int row = idx >> 4, f4 = idx & 15;
        const float* s = (f4 < 8) ? sg : su;
        int n4 = (f4 & 7) * 4;
        float4 v = *(const float4*)(s + (size_t)(k0 + row) * MD + n0s + n4);
        *(float4*)(&T[row * 67 + (f4 >> 3) * 32 + n4]) = v;
    }
    __syncthreads();
    const int KC = HD / 8;   // 128 k-chunks per column group
    #pragma unroll
    for (int p = 0; p < 2; p++) {
        int cid = p * 256 + tid;
        int g = cid >> 7, rem = cid & 127;
        int kc = rem >> 4, ni = rem & 15;
        int colT = (ni & 1) * 32 + ((g * 16 + ni) >> 1);
        u16x8 r;
        #pragma unroll
        for (int j = 0; j < 8; j++) r[j] = f2bf(T[(kc * 8 + j) * 67 + colT]);
        size_t oidx = ((size_t)((n0s >> 3) + g) * KC + (k0 >> 3) + kc) * 128 + ni * 8;
        *(u16x8*)(dst + oidx) = r;
    }
}

// ---------------- K0c: down fp32 [e][K=MD][N=HD] -> blocked bf16 ----------
__global__ __launch_bounds__(256) void k_cvt_d(
    const float* __restrict__ wr, const float* __restrict__ wsd,
    unsigned short* __restrict__ o)
{
    int e = blockIdx.z;
    const float* src = (e < NE) ? wr + (size_t)e * MD * HD : wsd;
    unsigned short* dst = o + (size_t)e * MD * HD;
    int k0 = blockIdx.x * 64, n0 = blockIdx.y * 64;
    __shared__ float T[64 * 67];
    int tid = threadIdx.x;
    #pragma unroll
    for (int p = 0; p < 4; p++) {
        int idx = p * 256 + tid;
        int row = idx >> 4, n4 = (idx & 15) * 4;
        float4 v = *(const float4*)(src + (size_t)(k0 + row) * HD + n0 + n4);
        *(float4*)(&T[row * 67 + n4]) = v;
    }
    __syncthreads();
    const int KC = MD / 8;   // 256
    #pragma unroll
    for (int p = 0; p < 2; p++) {
        int cid = p * 256 + tid;
        int g = cid >> 7, rem = cid & 127;
        int kc = rem >> 4, ni = rem & 15;
        u16x8 r;
        #pragma unroll
        for (int j = 0; j < 8; j++) r[j] = f2bf(T[(kc * 8 + j) * 67 + g * 16 + ni]);
        size_t oidx = ((size_t)((n0 >> 4) + g) * KC + (k0 >> 3) + kc) * 128 + ni * 8;
        *(u16x8*)(dst + oidx) = r;
    }
}

// ---------------- K1: routing (one wave per token, fp32) ----------------
__global__ __launch_bounds__(256) void k_route(
    const float* __restrict__ x, const float* __restrict__ gw,
    const float* __restrict__ beta,
    int* __restrict__ cnt, int* __restrict__ list, int* __restrict__ slot,
    float* __restrict__ rprob)
{
    int wave = threadIdx.x >> 6, lane = threadIdx.x & 63;
    int t = blockIdx.x * 4 + wave;
    const float4* xp = (const float4*)(x + (size_t)t * HD) + lane * 4;
    float4 xv[4];
    #pragma unroll
    for (int j = 0; j < 4; j++) xv[j] = xp[j];

    float logit[NE];
    #pragma unroll
    for (int e = 0; e < NE; e++) {
        const float4* gp = (const float4*)(gw + e * HD) + lane * 4;
        float s = 0.f;
        #pragma unroll
        for (int j = 0; j < 4; j++) {
            float4 g = gp[j];
            s += xv[j].x * g.x + xv[j].y * g.y + xv[j].z * g.z + xv[j].w * g.w;
        }
        for (int off = 32; off > 0; off >>= 1) s += __shfl_xor(s, off);
        logit[e] = s;
    }
    if (lane == 0) {
        float v[NE];
        #pragma unroll
        for (int e = 0; e < NE; e++) v[e] = logit[e] + beta[e];
        int i1 = 0; float m1 = v[0];
        #pragma unroll
        for (int e = 1; e < NE; e++) if (v[e] > m1) { m1 = v[e]; i1 = e; }
        int i2 = -1; float m2 = -3.4e38f;
        #pragma unroll
        for (int e = 0; e < NE; e++) if (e != i1 && v[e] > m2) { m2 = v[e]; i2 = e; }
        if (i2 < 0) i2 = (i1 + 1) & 7;
        float p1 = 1.f / (1.f + __expf(-logit[i1]));
        float p2 = 1.f / (1.f + __expf(-logit[i2]));
        int pos1 = atomicAdd(cnt + i1, 1);
        list[i1 * NT + pos1] = t; slot[t * 2 + 0] = (i1 << 16) | pos1; rprob[t * 2 + 0] = p1;
        int pos2 = atomicAdd(cnt + i2, 1);
        list[i2 * NT + pos2] = t; slot[t * 2 + 1] = (i2 << 16) | pos2; rprob[t * 2 + 1] = p2;
    }
}

// ---------------- K2: tiny scan for row bases (16-aligned for slabs) ------
__global__ void k_scan(const int* __restrict__ cnt, int* __restrict__ base) {
    if (threadIdx.x == 0) {
        int run = 0;
        for (int e = 0; e < NE; e++) { base[e] = run; run += (cnt[e] + 15) & ~15; }
        base[NE] = run;
    }
}

// ---------------- K3: gathered gate+up GEMM over interleaved blocked B ----
// B staged slab-wise: 1 gld16 per wave = one 16col x 32k slab, sequential.
// A (tokens) stays row-major gathered with source-side chunk swizzle.
__global__ __launch_bounds__(256, 4) void k_gateup(
    const unsigned short* __restrict__ x,
    const unsigned short* __restrict__ wgu,
    const int* __restrict__ cnt, const int* __restrict__ base, const int* __restrict__ list,
    unsigned short* __restrict__ h)
{
    int e = blockIdx.z;
    int i0 = blockIdx.y * 128;
    int n0 = blockIdx.x * 128;              // interleaved col space [0, 2*MD)
    int cnte = (e < NE) ? cnt[e] : NT;
    if (i0 >= cnte) return;
    int rbase = (e < NE) ? base[e] : NSH;
    const unsigned short* wb = wgu + (size_t)e * (2 * MD) * HD;

    __shared__ short As[2][128 * 32];
    __shared__ short Bs[2][8 * 512];        // 8 slabs of [4 chunk][16 ni][8 k]
    __shared__ int tok[128];

    int tid = threadIdx.x;
    int lane = tid & 63, wave = tid >> 6;
    if (tid < 128) {
        int gi = i0 + tid;
        tok[tid] = (e < NE) ? ((gi < cnte) ? list[e * NT + gi] : list[e * NT]) : gi;
    }
    __syncthreads();

    int rr = wave * 32 + (lane >> 2);
    int kc = ((lane & 3) ^ ((lane >> 3) & 3)) * 8;   // A source chunk swizzle
    size_t gaA0 = (size_t)tok[rr] * HD + kc;
    size_t gaA1 = (size_t)tok[rr + 16] * HD + kc;
    const int KC = HD / 8;   // 128
    size_t gaB0 = ((size_t)((n0 >> 4) + 2 * wave) * KC) * 128 + lane * 8;
    size_t gaB1 = gaB0 + (size_t)KC * 128;
    int loA0 = (wave * 32) * 32, loA1 = (wave * 32 + 16) * 32;
    int loB0 = (2 * wave) * 512, loB1 = (2 * wave + 1) * 512;

    int wr = (wave >> 1) * 64, wc = (wave & 1) * 64;
    int m = lane & 15, q = lane >> 4;
    int sa = (m >> 1) & 3;                  // A read-side swizzle (yields true chunk q)

    f32x4 acc[4][4];
    #pragma unroll
    for (int a = 0; a < 4; a++)
        #pragma unroll
        for (int b = 0; b < 4; b++) acc[a][b] = (f32x4)0.f;

    gld16(x + gaA0, &As[0][loA0]);
    gld16(x + gaA1, &As[0][loA1]);
    gld16(wb + gaB0, &Bs[0][loB0]);
    gld16(wb + gaB1, &Bs[0][loB1]);

    int it = 0;
    for (int k0 = 0; k0 < HD; k0 += 32, it ^= 1) {
        __syncthreads();   // drains this buf's prefetch (issued one iter ago)
        int nk = k0 + 32;
        if (nk < HD) {
            int nb = it ^ 1;
            gld16(x + gaA0 + nk, &As[nb][loA0]);
            gld16(x + gaA1 + nk, &As[nb][loA1]);
            gld16(wb + gaB0 + (size_t)nk * 16, &Bs[nb][loB0]);
            gld16(wb + gaB1 + (size_t)nk * 16, &Bs[nb][loB1]);
        }
        s16x8 af[4];
        #pragma unroll
        for (int ti = 0; ti < 4; ti++)
            af[ti] = *(const s16x8*)(&As[it][(wr + ti * 16 + m) * 32 + (q ^ sa) * 8]);
        #pragma unroll
        for (int tj = 0; tj < 4; tj++) {
            s16x8 bf = *(const s16x8*)(&Bs[it][((wave & 1) * 4 + tj) * 512 + q * 128 + m * 8]);
            #pragma unroll
            for (int ti = 0; ti < 4; ti++)
                acc[ti][tj] = __builtin_amdgcn_mfma_f32_16x16x32_bf16(af[ti], bf, acc[ti][tj], 0, 0, 0);
        }
    }
    // epilogue: pair gate/up across adjacent lanes; even lanes write silu(g)*u
    // into blocked h. D layout: row = q*4+r, col = m.
    #pragma unroll
    for (int ti = 0; ti < 4; ti++)
        #pragma unroll
        for (int tj = 0; tj < 4; tj++)
            #pragma unroll
            for (int r = 0; r < 4; r++) {
                float v = acc[ti][tj][r];
                float uo = __shfl_xor(v, 1);
                int gi = i0 + wr + ti * 16 + q * 4 + r;
                if (!(m & 1) && gi < cnte) {
                    float g = v;
                    float hv = (g / (1.f + __expf(-g))) * uo;
                    int col = (n0 + wc + tj * 16 + m) >> 1;
                    int rw = rbase + gi;
                    size_t hi = ((size_t)(rw >> 4) * (MD >> 3) + (col >> 3)) * 128
                              + (rw & 15) * 8 + (col & 7);
                    h[hi] = f2bf(hv);
                }
            }
}

// ---------------- K4: down projection, both operands slab-blocked ---------
__global__ __launch_bounds__(256, 4) void k_down(
    const unsigned short* __restrict__ wd_all,
    const int* __restrict__ cnt, const int* __restrict__ base,
    const unsigned short* __restrict__ h, unsigned short* __restrict__ eo)
{
    int e = blockIdx.z;
    int i0 = blockIdx.y * 128;
    int n0 = blockIdx.x * 128;
    int cnte = (e < NE) ? cnt[e] : NT;
    if (i0 >= cnte) return;
    int rbase = (e < NE) ? base[e] : NSH;
    const unsigned short* wd = wd_all + (size_t)e * MD * HD;

    __shared__ short As[2][8 * 512];
    __shared__ short Bd[2][8 * 512];

    int tid = threadIdx.x;
    int lane = tid & 63, wave = tid >> 6;
    int r0 = rbase + i0;                    // 16-aligned (padded bases)
    const int KC = MD / 8;   // 256
    size_t gaA0 = ((size_t)((r0 >> 4) + 2 * wave) * KC) * 128 + lane * 8;
    size_t gaA1 = gaA0 + (size_t)KC * 128;
    size_t gaB0 = ((size_t)((n0 >> 4) + 2 * wave) * KC) * 128 + lane * 8;
    size_t gaB1 = gaB0 + (size_t)KC * 128;
    int lo0 = (2 * wave) * 512, lo1 = (2 * wave + 1) * 512;

    int wr = (wave >> 1) * 64, wc = (wave & 1) * 64;
    int m = lane & 15, q = lane >> 4;

    f32x4 acc[4][4];
    #pragma unroll
    for (int a = 0; a < 4; a++)
        #pragma unroll
        for (int b = 0; b < 4; b++) acc[a][b] = (f32x4)0.f;

    gld16(h + gaA0, &As[0][lo0]);
    gld16(h + gaA1, &As[0][lo1]);
    gld16(wd + gaB0, &Bd[0][lo0]);
    gld16(wd + gaB1, &Bd[0][lo1]);

    int it = 0;
    for (int k0 = 0; k0 < MD; k0 += 32, it ^= 1) {
        __syncthreads();
        int nk = k0 + 32;
        if (nk < MD) {
            int nb = it ^ 1;
            gld16(h + gaA0 + (size_t)nk * 16, &As[nb][lo0]);
            gld16(h + gaA1 + (size_t)nk * 16, &As[nb][lo1]);
            gld16(wd + gaB0 + (size_t)nk * 16, &Bd[nb][lo0]);
            gld16(wd + gaB1 + (size_t)nk * 16, &Bd[nb][lo1]);
        }
        s16x8 af[4];
        #pragma unroll
        for (int ti = 0; ti < 4; ti++)
            af[ti] = *(const s16x8*)(&As[it][((wave >> 1) * 4 + ti) * 512 + q * 128 + m * 8]);
        #pragma unroll
        for (int tj = 0; tj < 4; tj++) {
            s16x8 bd = *(const s16x8*)(&Bd[it][((wave & 1) * 4 + tj) * 512 + q * 128 + m * 8]);
            #pragma unroll
            for (int ti = 0; ti < 4; ti++)
                acc[ti][tj] = __builtin_amdgcn_mfma_f32_16x16x32_bf16(af[ti], bd, acc[ti][tj], 0, 0, 0);
        }
    }
    #pragma unroll
    for (int ti = 0; ti < 4; ti++)
        #pragma unroll
        for (int tj = 0; tj < 4; tj++)
            #pragma unroll
            for (int r = 0; r < 4; r++) {
                int gi = i0 + wr + ti * 16 + q * 4 + r;
                if (gi < cnte) {
                    int col = n0 + wc + tj * 16 + m;
                    eo[(size_t)(rbase + gi) * HD + col] = f2bf(acc[ti][tj][r]);
                }
            }
}

// ---------------- K5: weighted combine -> fp32 out ----------------
__global__ __launch_bounds__(256) void k_combine(
    const unsigned short* __restrict__ eo, const int* __restrict__ slot,
    const float* __restrict__ rprob, const int* __restrict__ base,
    float* __restrict__ out)
{
    int t = blockIdx.x;
    int s0 = slot[t * 2], s1 = slot[t * 2 + 1];
    float p0 = rprob[t * 2], p1 = rprob[t * 2 + 1];
    int r0 = base[s0 >> 16] + (s0 & 0xFFFF);
    int r1 = base[s1 >> 16] + (s1 & 0xFFFF);
    int rs = NSH + t;
    int c = threadIdx.x * 4;
    u16x4 a = *(const u16x4*)(eo + (size_t)r0 * HD + c);
    u16x4 b = *(const u16x4*)(eo + (size_t)r1 * HD + c);
    u16x4 s = *(const u16x4*)(eo + (size_t)rs * HD + c);
    float4 res;
    res.x = p0 * bf2f(a[0]) + p1 * bf2f(b[0]) + bf2f(s[0]);
    res.y = p0 * bf2f(a[1]) + p1 * bf2f(b[1]) + bf2f(s[1]);
    res.z = p0 * bf2f(a[2]) + p1 * bf2f(b[2]) + bf2f(s[2]);
    res.w = p0 * bf2f(a[3]) + p1 * bf2f(b[3]) + bf2f(s[3]);
    *(float4*)(out + (size_t)t * HD + c) = res;
}

extern "C" void kernel_launch(void* const* d_in, const int* in_sizes, int n_in,
                              void* d_out, int out_size, void* d_ws, size_t ws_size,
                              hipStream_t stream)
{
    const float* x    = (const float*)d_in[0];
    const float* gw   = (const float*)d_in[1];
    const float* beta = (const float*)d_in[2];
    const float* wg   = (const float*)d_in[3];
    const float* wu   = (const float*)d_in[4];
    const float* wd   = (const float*)d_in[5];
    const float* swg  = (const float*)d_in[6];
    const float* swu  = (const float*)d_in[7];
    const float* swd  = (const float*)d_in[8];
    float* out = (float*)d_out;

    char* ws = (char*)d_ws;
    const size_t MB = (size_t)1 << 20;
    int*   cnt   = (int*)(ws + 0);
    int*   basep = (int*)(ws + 64);
    int*   list  = (int*)(ws + 1024);
    int*   slot  = (int*)(ws + 1024 + 65536);
    float* rprob = (float*)(ws + 1024 + 65536 + 16384);
    unsigned short* xb   = (unsigned short*)(ws + 1 * MB);    // [2048][1024]
    unsigned short* eo   = (unsigned short*)(ws + 6 * MB);    // [6272][1024]
    unsigned short* wgut = (unsigned short*)(ws + 20 * MB);   // [9] blocked interleaved [4096 x 1024]
    unsigned short* wdt  = (unsigned short*)(ws + 92 * MB);   // [9] blocked [1024 x 2048]
    unsigned short* h    = (unsigned short*)(ws + 128 * MB);  // [6272 x 2048] blocked

    hipMemsetAsync(ws, 0, 128, stream);

    const int NX = NT * HD;
    k_cvt<<<512, 256, 0, stream>>>(x, xb, NX);

    dim3 tgu(HD / 64, MD / 32, NE + 1);
    k_cvt_gu<<<tgu, 256, 0, stream>>>(wg, wu, swg, swu, wgut);
    dim3 td(MD / 64, HD / 64, NE + 1);
    k_cvt_d<<<td, 256, 0, stream>>>(wd, swd, wdt);

    k_route<<<NT / 4, 256, 0, stream>>>(x, gw, beta, cnt, list, slot, rprob);
    k_scan<<<1, 64, 0, stream>>>(cnt, basep);

    dim3 g3(2 * MD / 128, NT / 128, NE + 1);
    k_gateup<<<g3, 256, 0, stream>>>(xb, wgut, cnt, basep, list, h);

    dim3 g4(HD / 128, NT / 128, NE + 1);
    k_down<<<g4, 256, 0, stream>>>(wdt, cnt, basep, h, eo);

    k_combine<<<NT, 256, 0, stream>>>(eo, slot, rprob, basep, out);
}